// Round 9
// baseline (537.428 us; speedup 1.0000x reference)
//
#include <hip/hip_runtime.h>
#include <hip/hip_cooperative_groups.h>
#include <math.h>

namespace cg = cooperative_groups;

#define HAND_PARAM_DIM 32
#define INF_DIST 1000000.0f
#define EPS 1e-8f
#define NROW 64        // B*S
#define HW_N 65536
#define NV 778
#define NMESH 1556
#define NMESH_PAD 1568  // 8 slices * 196
#define SLICE 196
#define NSLICE 8
#define K_SEL 1024u
#define HALF_BITS  0x3F000000u  // bits of 0.5f
#define GUESS_BITS 0x3F733333u  // bits of 0.95f (speculative collect threshold)
#define CHUNK_SLOT 512u         // per-(row,chunk) candidate capacity (+21 sigma)
#define NBLK 512
#define FIX_SCALE 4294967296.0  // 2^32 fixed-point scale

// ---- workspace layout (bytes) ----
#define OFF_CAND 0u             // 64*16*512*8 = 4194304
#define OFF_CCNT 4194304u       // 64*16*4     = 4096
#define OFF_CTR  4198400u       // 4 u32: gsum(2), gcnt, done (8-aligned)
#define OFF_MESH 4198416u       // 64*1568*16  = 1605632 (16-aligned)
#define OFF_SAMP 5804048u       // 64*1024*16  = 1048576
#define OFF_MINP 6852624u       // 64*8*1024*4 = 2097152

typedef unsigned long long u64;

struct Params {
    const float* mask; const float* means; const int* hv; const float* hp;
    const float* vtl; const float* vtr;
    const float* sdl; const float* sdr;
    const float* pdl; const float* pdr;
    u64* cand; unsigned* ccnt; unsigned* ctr;
    float4* meshP; float4* sampbuf; float* minpart; float* out;
};

union SMem {
    struct { u64 loc[CHUNK_SLOT]; unsigned nc, nbad; } a;                 // 4112 B
    struct { unsigned h[256], seg[256], csub[16], tlist[256];
             unsigned sbin, sRn, sbad, stot, tn, scut, ns; } b;           // ~3200 B
    struct { float4 mq[SLICE]; } c;                                       // 3136 B
    struct { long long rs[256]; unsigned rc[256]; } d;                    // 3072 B
};

// ---------------------------------------------------------------------------
// Phase A1: speculative collect, 2 chunks per block (one mask pass total).
// Per-(row,chunk) private slot range + count word -> NO global atomics.
// ---------------------------------------------------------------------------
__device__ __forceinline__ void collect2(const Params& P, SMem& sm, int blk) {
    int t = threadIdx.x;
    for (int cc = 0; cc < 2; cc++) {
        int g = blk * 2 + cc;
        int row = g >> 4, chunk = g & 15;
        if (!(P.hv[row*2] | P.hv[row*2+1])) continue;   // block-uniform
        if (t == 0) { sm.a.nc = 0u; sm.a.nbad = 0u; }
        __syncthreads();
        const float4* m4 = (const float4*)(P.mask + (size_t)row * HW_N + chunk * 4096);
#pragma unroll
        for (int k = 0; k < 4; k++) {
            float4 v = m4[k*256 + t];
            unsigned e0 = (unsigned)(chunk*4096 + (k*256 + t)*4);
            unsigned u;
#define PROC(comp, off_) { u = __float_as_uint(comp); \
            if (u - GUESS_BITS < 0x10000u) { \
                unsigned p_ = atomicAdd(&sm.a.nc, 1u); \
                if (p_ < CHUNK_SLOT) sm.a.loc[p_] = ((u64)u << 32) | (e0 + off_); \
            } else if (u >= GUESS_BITS + 0x10000u && u < 0x80000000u) sm.a.nbad = 1u; }
            PROC(v.x, 0u) PROC(v.y, 1u) PROC(v.z, 2u) PROC(v.w, 3u)
#undef PROC
        }
        __syncthreads();
        unsigned n = (sm.a.nc < CHUNK_SLOT) ? sm.a.nc : CHUNK_SLOT;
        if (t == 0) P.ccnt[row*16 + chunk] = sm.a.nc | (sm.a.nbad << 31);
        u64* dst = P.cand + (size_t)(row*16 + chunk) * CHUNK_SLOT;
        for (unsigned i = t; i < n; i += 256) dst[i] = sm.a.loc[i];
        __syncthreads();
    }
}

// ---------------------------------------------------------------------------
// Phase A2: MANO mesh job (row, hand). Pre-scaled: m.xyz=-2p, m.w=|p|^2.
// ---------------------------------------------------------------------------
__device__ __forceinline__ void mesh_job(const Params& P, int mb) {
    int t = threadIdx.x;
    int row  = mb >> 1;
    int hand = mb & 1;
    const float* p = P.hp + row * (2 * HAND_PARAM_DIM) + hand * HAND_PARAM_DIM;
    int valid = P.hv[row * 2 + hand];

    const float* vt = hand ? P.vtr : P.vtl;
    const float* sd = hand ? P.sdr : P.sdl;
    const float* pd = hand ? P.pdr : P.pdl;

    if (hand == 1 && t < (NMESH_PAD - NMESH))
        P.meshP[row * NMESH_PAD + NMESH + t] = make_float4(0.f, 0.f, 0.f, 3.4e38f);

    float tx = p[0], ty = p[1], tz = p[2];
    float q0 = p[3], q1 = p[4], q2 = p[5], q3 = p[6];
    float qn = sqrtf(q0*q0 + q1*q1 + q2*q2 + q3*q3 + EPS);
    float inv = 1.0f / fmaxf(qn, EPS);
    q0 *= inv; q1 *= inv; q2 *= inv; q3 *= inv;
    float sgn = (q0 < 0.0f) ? -1.0f : 1.0f;
    q0 *= sgn; q1 *= sgn; q2 *= sgn; q3 *= sgn;
    float sin_half = sqrtf(q1*q1 + q2*q2 + q3*q3 + EPS);
    float w_safe = fminf(fmaxf(q0, -1.0f + EPS), 1.0f - EPS);
    float ang2 = 2.0f * atan2f(sin_half, w_safe);
    float factor = (sin_half < 1e-6f) ? 2.0f : ang2 / fmaxf(sin_half, EPS);
    float rx = q1 * factor, ry = q2 * factor, rz = q3 * factor;
    float ang = sqrtf(rx*rx + ry*ry + rz*rz + EPS);
    float iang = 1.0f / ang;
    float ax = rx * iang, ay = ry * iang, az = rz * iang;
    float c = cosf(ang), s = sinf(ang), omc = 1.0f - c;

    float pose[15], betas[10];
#pragma unroll
    for (int k = 0; k < 15; k++) pose[k] = p[7 + k];
#pragma unroll
    for (int k = 0; k < 10; k++) betas[k] = p[22 + k];

    for (int v = t; v < NV; v += 256) {
        float px = vt[v*3+0], py = vt[v*3+1], pz = vt[v*3+2];
        const float* sdv = sd + v * 30;
#pragma unroll
        for (int k = 0; k < 10; k++) {
            px = fmaf(sdv[k],      betas[k], px);
            py = fmaf(sdv[10 + k], betas[k], py);
            pz = fmaf(sdv[20 + k], betas[k], pz);
        }
        const float* pdv = pd + v * 45;
#pragma unroll
        for (int k = 0; k < 15; k++) {
            px = fmaf(pdv[k],      pose[k], px);
            py = fmaf(pdv[15 + k], pose[k], py);
            pz = fmaf(pdv[30 + k], pose[k], pz);
        }
        float cx = ay * pz - az * py;
        float cy = az * px - ax * pz;
        float cz = ax * py - ay * px;
        float kdv = ax * px + ay * py + az * pz;
        float ox = px * c + cx * s + ax * kdv * omc + tx;
        float oy = py * c + cy * s + ay * kdv * omc + ty;
        float oz = pz * c + cz * s + az * kdv * omc + tz;
        if (!valid) { ox = INF_DIST; oy = INF_DIST; oz = INF_DIST; }
        float sb = fmaf(ox, ox, fmaf(oy, oy, oz * oz));
        P.meshP[row * NMESH_PAD + hand * NV + v] = make_float4(-2.0f*ox, -2.0f*oy, -2.0f*oz, sb);
    }
}

// ---------------------------------------------------------------------------
// Phase B: per-row exact top-1024. Fast: 2-phase radix on (bits-GUESS)
// reading candidates from global (L2-hot). Generic 4-phase mask fallback.
// Emits sampbuf[row][i] = (x,y,z, val>0.5 ? |s|^2 : -1). Row 0 zeroes ctr.
// ---------------------------------------------------------------------------
__device__ __forceinline__ void select_row(const Params& P, SMem& sm, int row) {
    int t = threadIdx.x;
    if (row == 0 && t < 4) P.ctr[t] = 0u;           // gsum lo/hi, gcnt, done
    for (unsigned i = t; i < K_SEL; i += 256)
        P.sampbuf[(size_t)row * K_SEL + i] = make_float4(0.f, 0.f, 0.f, -1.0f);
    if (!(P.hv[row*2] | P.hv[row*2+1])) return;

    if (t == 0) { sm.b.sbad = 0u; sm.b.stot = 0u; sm.b.tn = 0u; sm.b.ns = 0u; }
    __syncthreads();
    if (t < 16) {
        unsigned w = P.ccnt[row*16 + t];
        unsigned n = w & 0x7FFFFFFFu;
        unsigned cs = (n < CHUNK_SLOT) ? n : CHUNK_SLOT;
        sm.b.csub[t] = cs;
        if ((w >> 31) || n > CHUNK_SLOT) atomicOr(&sm.b.sbad, 1u);
        atomicAdd(&sm.b.stot, cs);
    }
    __syncthreads();
    unsigned cnt = sm.b.stot;
    bool ok = (sm.b.sbad == 0u) && (cnt >= K_SEL);
    const float* mrow = P.mask + (size_t)row * HW_N;

    unsigned T, R;
    if (ok) {
        unsigned pfx = 0u; R = K_SEL;
        for (int ph = 0; ph < 2; ph++) {
            sm.b.h[t] = 0u;
            __syncthreads();
            for (int c2 = 0; c2 < 16; c2++) {
                unsigned n = sm.b.csub[c2];
                const u64* src = P.cand + (size_t)(row*16 + c2) * CHUNK_SLOT;
                for (unsigned i = t; i < n; i += 256) {
                    unsigned off = (unsigned)(src[i] >> 32) - GUESS_BITS;
                    if (ph == 0) atomicAdd(&sm.b.h[off >> 8], 1u);
                    else if ((off >> 8) == pfx) atomicAdd(&sm.b.h[off & 0xFFu], 1u);
                }
            }
            __syncthreads();
            sm.b.seg[t] = sm.b.h[t];
            __syncthreads();
            for (int o = 1; o < 256; o <<= 1) {      // inclusive suffix scan
                unsigned v = (t + o < 256) ? sm.b.seg[t + o] : 0u;
                __syncthreads(); sm.b.seg[t] += v; __syncthreads();
            }
            unsigned excl = (t < 255) ? sm.b.seg[t + 1] : 0u;
            if (excl < R && R <= sm.b.seg[t]) { sm.b.sbin = (unsigned)t; sm.b.sRn = R - excl; }
            __syncthreads();
            pfx = (ph == 0) ? sm.b.sbin : ((pfx << 8) | sm.b.sbin);
            R = sm.b.sRn;
            __syncthreads();
        }
        T = GUESS_BITS + pfx;
    } else {
        unsigned pfx = 0u; R = K_SEL;
        for (int ph = 0; ph < 4; ph++) {
            int sh = 24 - 8 * ph;
            unsigned pm = (ph == 0) ? 0u : (0xFFFFFFFFu << (sh + 8));
            sm.b.h[t] = 0u;
            __syncthreads();
            for (int i = t; i < HW_N; i += 256) {
                unsigned u = __float_as_uint(mrow[i]);
                if ((u & pm) == pfx) atomicAdd(&sm.b.h[(u >> sh) & 0xFFu], 1u);
            }
            __syncthreads();
            sm.b.seg[t] = sm.b.h[t];
            __syncthreads();
            for (int o = 1; o < 256; o <<= 1) {
                unsigned v = (t + o < 256) ? sm.b.seg[t + o] : 0u;
                __syncthreads(); sm.b.seg[t] += v; __syncthreads();
            }
            unsigned excl = (t < 255) ? sm.b.seg[t + 1] : 0u;
            if (excl < R && R <= sm.b.seg[t]) { sm.b.sbin = (unsigned)t; sm.b.sRn = R - excl; }
            __syncthreads();
            pfx |= sm.b.sbin << sh;
            R = sm.b.sRn;
            __syncthreads();
        }
        T = pfx;
    }

    // ties at exact value T -> R-th smallest index is the cut
    if (ok) {
        for (int c2 = 0; c2 < 16; c2++) {
            unsigned n = sm.b.csub[c2];
            const u64* src = P.cand + (size_t)(row*16 + c2) * CHUNK_SLOT;
            for (unsigned i = t; i < n; i += 256) {
                u64 e = src[i];
                if ((unsigned)(e >> 32) == T) {
                    unsigned p_ = atomicAdd(&sm.b.tn, 1u);
                    if (p_ < 256u) sm.b.tlist[p_] = (unsigned)e;
                }
            }
        }
    } else {
        for (int i = t; i < HW_N; i += 256) {
            if (__float_as_uint(mrow[i]) == T) {
                unsigned p_ = atomicAdd(&sm.b.tn, 1u);
                if (p_ < 256u) sm.b.tlist[p_] = (unsigned)i;
            }
        }
    }
    __syncthreads();
    if (t == 0) {
        unsigned n2 = (sm.b.tn < 256u) ? sm.b.tn : 256u;
        for (unsigned a = 1; a < n2; a++) {
            unsigned key = sm.b.tlist[a]; int b = (int)a - 1;
            while (b >= 0 && sm.b.tlist[b] > key) { sm.b.tlist[b+1] = sm.b.tlist[b]; b--; }
            sm.b.tlist[b+1] = key;
        }
        unsigned r = R;
        if (r > n2) r = n2;
        if (r < 1u) r = 1u;
        sm.b.scut = (n2 > 0u) ? sm.b.tlist[r - 1] : 0u;
    }
    __syncthreads();
    unsigned cut = sm.b.scut;

    // write selected set (slot order free; downstream sums are order-free)
    if (ok) {
        for (int c2 = 0; c2 < 16; c2++) {
            unsigned n = sm.b.csub[c2];
            const u64* src = P.cand + (size_t)(row*16 + c2) * CHUNK_SLOT;
            for (unsigned i = t; i < n; i += 256) {
                u64 e = src[i];
                unsigned u = (unsigned)(e >> 32), id = (unsigned)e;
                if (u > T || (u == T && id <= cut)) {
                    unsigned p_ = atomicAdd(&sm.b.ns, 1u);
                    if (p_ < K_SEL) {
                        const float* gm = P.means + ((size_t)row * HW_N + id) * 3;
                        float sx = gm[0], sy = gm[1], sz = gm[2];
                        float sa = fmaf(sx, sx, fmaf(sy, sy, sz * sz));
                        float w  = (u > HALF_BITS) ? sa : -1.0f;
                        P.sampbuf[(size_t)row * K_SEL + p_] = make_float4(sx, sy, sz, w);
                    }
                }
            }
        }
    } else {
        for (int i = t; i < HW_N; i += 256) {
            unsigned u = __float_as_uint(mrow[i]);
            if (u > T || (u == T && (unsigned)i <= cut)) {
                unsigned p_ = atomicAdd(&sm.b.ns, 1u);
                if (p_ < K_SEL) {
                    const float* gm = P.means + ((size_t)row * HW_N + i) * 3;
                    float sx = gm[0], sy = gm[1], sz = gm[2];
                    float sa = fmaf(sx, sx, fmaf(sy, sy, sz * sz));
                    float w  = (u > HALF_BITS) ? sa : -1.0f;
                    P.sampbuf[(size_t)row * K_SEL + p_] = make_float4(sx, sy, sz, w);
                }
            }
        }
    }
}

// ---------------------------------------------------------------------------
// Phase C: NN partial mins. blk -> (row, slice of 196). 4 samples/lane in
// regs; broadcast LDS point reads. No atomics, no fences.
// ---------------------------------------------------------------------------
__device__ __forceinline__ void dist_phase(const Params& P, SMem& sm, int blk) {
    int row = blk >> 3, sl = blk & 7;
    int t = threadIdx.x;
    if (t < SLICE) sm.c.mq[t] = P.meshP[row * NMESH_PAD + sl * SLICE + t];
    const float4* sb = P.sampbuf + (size_t)row * K_SEL;
    float sx[4], sy[4], sz[4], mn[4];
#pragma unroll
    for (int k = 0; k < 4; k++) {
        float4 s = sb[t + 256*k];
        sx[k] = s.x; sy[k] = s.y; sz[k] = s.z;
        mn[k] = 3.4e38f;
    }
    __syncthreads();
#pragma unroll 2
    for (int i = 0; i < SLICE; i++) {
        float4 a = sm.c.mq[i];
#pragma unroll
        for (int k = 0; k < 4; k++)
            mn[k] = fminf(mn[k], fmaf(sx[k], a.x, fmaf(sy[k], a.y, fmaf(sz[k], a.z, a.w))));
    }
    float* mp = P.minpart + ((size_t)row * NSLICE + sl) * K_SEL;
#pragma unroll
    for (int k = 0; k < 4; k++) mp[t + 256*k] = mn[k];
}

// ---------------------------------------------------------------------------
// Phase D: per-row min over 8 slices + fixed-point row sum + ticket finalize.
// Integer adds -> order-invariant -> bit-deterministic.
// ---------------------------------------------------------------------------
__device__ __forceinline__ void reduce_row(const Params& P, SMem& sm, int row) {
    int t = threadIdx.x;
    long long acc = 0; unsigned c = 0;
#pragma unroll
    for (int k = 0; k < 4; k++) {
        int j = k * 256 + t;
        const float* mp = P.minpart + (size_t)row * NSLICE * K_SEL + j;
        float m = mp[0];
#pragma unroll
        for (int s = 1; s < NSLICE; s++) m = fminf(m, mp[s * (int)K_SEL]);
        float4 sp = P.sampbuf[(size_t)row * K_SEL + j];
        if (sp.w >= 0.0f) {
            float d2 = fmaxf(m + sp.w, 0.0f);
            acc += (long long)((double)d2 * FIX_SCALE);
            c += 1u;
        }
    }
    sm.d.rs[t] = acc; sm.d.rc[t] = c;
    __syncthreads();
    for (int off = 128; off > 0; off >>= 1) {
        if (t < off) { sm.d.rs[t] += sm.d.rs[t+off]; sm.d.rc[t] += sm.d.rc[t+off]; }
        __syncthreads();
    }
    if (t == 0) {
        atomicAdd((u64*)P.ctr, (u64)sm.d.rs[0]);
        atomicAdd(&P.ctr[2], sm.d.rc[0]);
        __threadfence();
        unsigned tk = atomicAdd(&P.ctr[3], 1u);
        if (tk == (unsigned)(NROW - 1)) {
            u64 sbits = atomicAdd((u64*)P.ctr, 0ull);
            unsigned cc = atomicAdd(&P.ctr[2], 0u);
            double sum = (double)(long long)sbits / FIX_SCALE;
            P.out[0] = (float)(sum / (double)(cc ? cc : 1u));
        }
    }
}

// ---------------------------------------------------------------------------
// Fused cooperative kernel: 512 blocks x 256 threads, 3 grid syncs.
// __launch_bounds__(256,2) caps VGPR<=256 -> 2 blocks/CU co-resident (LDS 4KB).
// ---------------------------------------------------------------------------
__global__ void __launch_bounds__(256, 2) fused_kernel(Params P) {
    __shared__ SMem sm;
    cg::grid_group grid = cg::this_grid();
    int blk = blockIdx.x;

    collect2(P, sm, blk);
    if ((blk & 3) == 0) mesh_job(P, blk >> 2);
    grid.sync();
    if (blk < NROW) select_row(P, sm, blk);
    grid.sync();
    dist_phase(P, sm, blk);
    grid.sync();
    if (blk < NROW) reduce_row(P, sm, blk);
}

// ---- fallback wrappers (regular launches; same device code) ----
__global__ void __launch_bounds__(256) k_prep(Params P) {
    __shared__ SMem sm;
    collect2(P, sm, blockIdx.x);
    if ((blockIdx.x & 3) == 0) mesh_job(P, blockIdx.x >> 2);
}
__global__ void __launch_bounds__(256) k_sel(Params P) {
    __shared__ SMem sm;
    select_row(P, sm, blockIdx.x);
}
__global__ void __launch_bounds__(256) k_dist(Params P) {
    __shared__ SMem sm;
    dist_phase(P, sm, blockIdx.x);
}
__global__ void __launch_bounds__(256) k_red(Params P) {
    __shared__ SMem sm;
    reduce_row(P, sm, blockIdx.x);
}

extern "C" void kernel_launch(void* const* d_in, const int* in_sizes, int n_in,
                              void* d_out, int out_size, void* d_ws, size_t ws_size,
                              hipStream_t stream) {
    char* ws = (char*)d_ws;
    Params p;
    p.hp    = (const float*)d_in[0];
    p.means = (const float*)d_in[1];
    p.mask  = (const float*)d_in[2];
    p.hv    = (const int*)  d_in[3];
    p.vtl   = (const float*)d_in[4];
    p.vtr   = (const float*)d_in[5];
    p.sdl   = (const float*)d_in[6];
    p.sdr   = (const float*)d_in[7];
    p.pdl   = (const float*)d_in[8];
    p.pdr   = (const float*)d_in[9];
    p.cand    = (u64*)(ws + OFF_CAND);
    p.ccnt    = (unsigned*)(ws + OFF_CCNT);
    p.ctr     = (unsigned*)(ws + OFF_CTR);
    p.meshP   = (float4*)(ws + OFF_MESH);
    p.sampbuf = (float4*)(ws + OFF_SAMP);
    p.minpart = (float*)(ws + OFF_MINP);
    p.out     = (float*)d_out;

    void* args[] = { (void*)&p };
    hipError_t err = hipLaunchCooperativeKernel(
        reinterpret_cast<void*>(fused_kernel), dim3(NBLK), dim3(256),
        args, 0, stream);
    if (err != hipSuccess) {
        // fallback: same phases as 4 regular launches (kernel-boundary sync)
        k_prep<<<NBLK, 256, 0, stream>>>(p);
        k_sel <<<NROW, 256, 0, stream>>>(p);
        k_dist<<<NBLK, 256, 0, stream>>>(p);
        k_red <<<NROW, 256, 0, stream>>>(p);
    }
}

// Round 10
// 93.602 us; speedup vs baseline: 5.7416x; 5.7416x over previous
//
#include <hip/hip_runtime.h>
#include <math.h>

#define HAND_PARAM_DIM 32
#define INF_DIST 1000000.0f
#define EPS 1e-8f
#define NROW 64        // B*S
#define HW_N 65536
#define NV 778
#define NMESH 1556
#define NMESH_PAD 1568  // 8 slices * 196
#define SLICE 196
#define NSLICE 8
#define K_SEL 1024u
#define HALF_BITS  0x3F000000u  // bits of 0.5f
#define GUESS_BITS 0x3F733333u  // bits of 0.95f (speculative collect threshold)
#define TOP_BITS   0x3F800000u  // bits of 1.0f
#define CHUNK_SLOT 512          // per-(row,chunk) candidate capacity (+21 sigma)
#define CAND_MAX   8192         // 16 * CHUNK_SLOT
#define FIX_SCALE 4294967296.0  // 2^32 fixed-point scale

// ---- workspace layout (bytes) ----
#define OFF_CAND 0u             // 64*16*512*8 = 4194304
#define OFF_CCNT 4194304u       // 64*16*4     = 4096
#define OFF_CTR  4198400u       // 4 u32: gsum(2), gcnt, done (8-aligned)
#define OFF_TICK 4198416u       // 64 u32 rowtick
#define OFF_MESH 4198672u       // 64*1568*16  = 1605632 (16-aligned)
#define OFF_SAMP 5804304u       // 64*1024*16  = 1048576
#define OFF_MINP 6852880u       // 64*8*1024*4 = 2097152

typedef unsigned long long u64;

// ---------------------------------------------------------------------------
// Kernel 1: blocks 0..1023 = speculative collect (one mask pass, NO global
// atomics: each (row,chunk) block owns cand slot range + count word);
// blocks 1024..1151 = MANO mesh points. (unchanged from R7's 57us version)
// Mesh stored pre-scaled: m.xyz = -2*p, m.w = |p|^2; NN metric is
// d = fma(sx,m.x, fma(sy,m.y, fma(sz,m.z, m.w))) = |p|^2 - 2 s.p
// ---------------------------------------------------------------------------
__global__ void __launch_bounds__(256) combo_kernel(
    const float* __restrict__ mask, const int* __restrict__ hv,
    u64* __restrict__ cand, unsigned* __restrict__ ccnt,
    const float* __restrict__ hp,
    const float* __restrict__ vtl, const float* __restrict__ vtr,
    const float* __restrict__ sdl, const float* __restrict__ sdr,
    const float* __restrict__ pdl, const float* __restrict__ pdr,
    float4* __restrict__ meshP)
{
    int blk = blockIdx.x;
    int t = threadIdx.x;

    if (blk < 1024) {
        __shared__ u64 loc[CHUNK_SLOT];
        __shared__ unsigned nc, nbad;
        int row = blk >> 4, chunk = blk & 15;
        if (!(hv[row*2] | hv[row*2+1])) return;   // ccnt never read for invalid rows
        if (t == 0) { nc = 0u; nbad = 0u; }
        __syncthreads();
        const float4* m4 = (const float4*)(mask + (size_t)row * HW_N + chunk * 4096);
#pragma unroll
        for (int k = 0; k < 4; k++) {
            float4 v = m4[k*256 + t];
            unsigned e0 = (unsigned)(chunk*4096 + (k*256 + t)*4);
            unsigned u;
#define PROC(comp, off_) { u = __float_as_uint(comp); \
            if (u >= GUESS_BITS) { \
                unsigned p_ = atomicAdd(&nc, 1u); \
                if (p_ < CHUNK_SLOT) loc[p_] = ((u64)u << 32) | (e0 + off_); \
                if (u >= TOP_BITS) nbad = 1u; } }
            PROC(v.x, 0u) PROC(v.y, 1u) PROC(v.z, 2u) PROC(v.w, 3u)
#undef PROC
        }
        __syncthreads();
        unsigned n = (nc < CHUNK_SLOT) ? nc : CHUNK_SLOT;
        if (t == 0) ccnt[row*16 + chunk] = nc | (nbad << 31);
        u64* dst = cand + ((size_t)(row*16 + chunk)) * CHUNK_SLOT;
        for (unsigned i = t; i < n; i += 256) dst[i] = loc[i];
        return;
    }

    // ---- mesh points ----
    int mb   = blk - 1024;
    int row  = mb >> 1;
    int hand = mb & 1;
    const float* p = hp + row * (2 * HAND_PARAM_DIM) + hand * HAND_PARAM_DIM;
    int valid = hv[row * 2 + hand];

    const float* vt = hand ? vtr : vtl;
    const float* sd = hand ? sdr : sdl;
    const float* pd = hand ? pdr : pdl;

    if (hand == 1 && t < (NMESH_PAD - NMESH))
        meshP[row * NMESH_PAD + NMESH + t] = make_float4(0.f, 0.f, 0.f, 3.4e38f);

    float tx = p[0], ty = p[1], tz = p[2];
    float q0 = p[3], q1 = p[4], q2 = p[5], q3 = p[6];
    float qn = sqrtf(q0*q0 + q1*q1 + q2*q2 + q3*q3 + EPS);
    float inv = 1.0f / fmaxf(qn, EPS);
    q0 *= inv; q1 *= inv; q2 *= inv; q3 *= inv;
    float sgn = (q0 < 0.0f) ? -1.0f : 1.0f;
    q0 *= sgn; q1 *= sgn; q2 *= sgn; q3 *= sgn;
    float sin_half = sqrtf(q1*q1 + q2*q2 + q3*q3 + EPS);
    float w_safe = fminf(fmaxf(q0, -1.0f + EPS), 1.0f - EPS);
    float ang2 = 2.0f * atan2f(sin_half, w_safe);
    float factor = (sin_half < 1e-6f) ? 2.0f : ang2 / fmaxf(sin_half, EPS);
    float rx = q1 * factor, ry = q2 * factor, rz = q3 * factor;
    float ang = sqrtf(rx*rx + ry*ry + rz*rz + EPS);
    float iang = 1.0f / ang;
    float ax = rx * iang, ay = ry * iang, az = rz * iang;
    float c = cosf(ang), s = sinf(ang), omc = 1.0f - c;

    float pose[15], betas[10];
#pragma unroll
    for (int k = 0; k < 15; k++) pose[k] = p[7 + k];
#pragma unroll
    for (int k = 0; k < 10; k++) betas[k] = p[22 + k];

    for (int v = t; v < NV; v += 256) {
        float px = vt[v*3+0], py = vt[v*3+1], pz = vt[v*3+2];
        const float* sdv = sd + v * 30;
#pragma unroll
        for (int k = 0; k < 10; k++) {
            px = fmaf(sdv[k],      betas[k], px);
            py = fmaf(sdv[10 + k], betas[k], py);
            pz = fmaf(sdv[20 + k], betas[k], pz);
        }
        const float* pdv = pd + v * 45;
#pragma unroll
        for (int k = 0; k < 15; k++) {
            px = fmaf(pdv[k],      pose[k], px);
            py = fmaf(pdv[15 + k], pose[k], py);
            pz = fmaf(pdv[30 + k], pose[k], pz);
        }
        float cx = ay * pz - az * py;
        float cy = az * px - ax * pz;
        float cz = ax * py - ay * px;
        float kdv = ax * px + ay * py + az * pz;
        float ox = px * c + cx * s + ax * kdv * omc + tx;
        float oy = py * c + cy * s + ay * kdv * omc + ty;
        float oz = pz * c + cz * s + az * kdv * omc + tz;
        if (!valid) { ox = INF_DIST; oy = INF_DIST; oz = INF_DIST; }
        float sb = fmaf(ox, ox, fmaf(oy, oy, oz * oz));
        meshP[row * NMESH_PAD + hand * NV + v] = make_float4(-2.0f*ox, -2.0f*oy, -2.0f*oz, sb);
    }
}

// ---------------------------------------------------------------------------
// Kernel 2: per-row exact top-1024 (unchanged from R7's 57us version, plus
// rowtick zeroing). Fast path: 2-phase radix on (bits - GUESS_BITS); generic
// 4-phase global fallback. Emits sampbuf[row][i] = (x,y,z, val>0.5?|s|^2:-1).
// ---------------------------------------------------------------------------
__global__ void __launch_bounds__(256) sel_fin_kernel(
    const float* __restrict__ mask, const float* __restrict__ means,
    const int* __restrict__ hv,
    const u64* __restrict__ cand, const unsigned* __restrict__ ccnt,
    float4* __restrict__ sampbuf, unsigned* __restrict__ ctr,
    unsigned* __restrict__ rowtick)
{
    __shared__ unsigned cval[CAND_MAX], cidx[CAND_MAX];   // 64 KB
    __shared__ unsigned h[256], seg[256];
    __shared__ unsigned csub[16], cbase[16];
    __shared__ unsigned sbin, sRn, sbad, stot;
    __shared__ unsigned tlist[256];
    __shared__ unsigned tn, ns, scut;
    int row = blockIdx.x, t = threadIdx.x;

    if (row == 0 && t < 4) ctr[t] = 0u;          // gsum lo/hi, gcnt, done
    if (t == 0) rowtick[row] = 0u;               // re-zero every call
    for (unsigned i = t; i < K_SEL; i += 256)
        sampbuf[(size_t)row * K_SEL + i] = make_float4(0.f, 0.f, 0.f, -1.0f);
    if (!(hv[row*2] | hv[row*2+1])) return;

    if (t == 0) { sbad = 0u; tn = 0u; ns = 0u; }
    __syncthreads();
    if (t < 16) {
        unsigned w = ccnt[row*16 + t];
        unsigned n = w & 0x7FFFFFFFu;
        csub[t] = (n < CHUNK_SLOT) ? n : CHUNK_SLOT;
        if ((w >> 31) || n > CHUNK_SLOT) atomicOr(&sbad, 1u);
    }
    __syncthreads();
    if (t == 0) {
        unsigned run = 0;
#pragma unroll
        for (int c = 0; c < 16; c++) { cbase[c] = run; run += csub[c]; }
        stot = run;
    }
    __syncthreads();
    unsigned cnt = stot;
    bool ok = (sbad == 0u) && (cnt >= K_SEL) && (cnt <= CAND_MAX);
    const float* mrow = mask + (size_t)row * HW_N;
    unsigned M = ok ? cnt : (unsigned)HW_N;

    if (ok) {
#pragma unroll
        for (int c = 0; c < 16; c++) {
            unsigned n = csub[c], b = cbase[c];
            const u64* src = cand + ((size_t)(row*16 + c)) * CHUNK_SLOT;
            for (unsigned i = t; i < n; i += 256) {
                u64 e = src[i];
                cval[b + i] = (unsigned)(e >> 32); cidx[b + i] = (unsigned)e;
            }
        }
    }
    __syncthreads();

    unsigned T, R;
    if (ok) {
        unsigned pfx = 0u; R = K_SEL;
        for (int ph = 0; ph < 2; ph++) {
            int sh = 8 * (1 - ph);
            h[t] = 0u;
            __syncthreads();
            for (unsigned i = t; i < cnt; i += 256) {
                unsigned off = cval[i] - GUESS_BITS;
                if (ph == 0 || (off >> 8) == pfx) atomicAdd(&h[(off >> sh) & 0xFFu], 1u);
            }
            __syncthreads();
            seg[t] = h[t];
            __syncthreads();
            for (int off2 = 1; off2 < 256; off2 <<= 1) {   // inclusive suffix scan
                unsigned v = (t + off2 < 256) ? seg[t + off2] : 0u;
                __syncthreads(); seg[t] += v; __syncthreads();
            }
            unsigned excl = (t < 255) ? seg[t + 1] : 0u;
            if (excl < R && R <= seg[t]) { sbin = (unsigned)t; sRn = R - excl; }
            __syncthreads();
            pfx = (ph == 0) ? sbin : ((pfx << 8) | sbin);
            R = sRn;
            __syncthreads();
        }
        T = GUESS_BITS + pfx;
    } else {
        unsigned pfx = 0u; R = K_SEL;
        for (int ph = 0; ph < 4; ph++) {
            int sh = 24 - 8 * ph;
            unsigned pm = (ph == 0) ? 0u : (0xFFFFFFFFu << (sh + 8));
            h[t] = 0u;
            __syncthreads();
            for (unsigned i = t; i < M; i += 256) {
                unsigned u = __float_as_uint(mrow[i]);
                if ((u & pm) == pfx) atomicAdd(&h[(u >> sh) & 0xFFu], 1u);
            }
            __syncthreads();
            seg[t] = h[t];
            __syncthreads();
            for (int off2 = 1; off2 < 256; off2 <<= 1) {
                unsigned v = (t + off2 < 256) ? seg[t + off2] : 0u;
                __syncthreads(); seg[t] += v; __syncthreads();
            }
            unsigned excl = (t < 255) ? seg[t + 1] : 0u;
            if (excl < R && R <= seg[t]) { sbin = (unsigned)t; sRn = R - excl; }
            __syncthreads();
            pfx |= sbin << sh;
            R = sRn;
            __syncthreads();
        }
        T = pfx;
    }

    // ---- ties at exact value T -> R-th smallest index is the cut ----
    for (unsigned i = t; i < M; i += 256) {
        unsigned u = ok ? cval[i] : __float_as_uint(mrow[i]);
        if (u == T) {
            unsigned p = atomicAdd(&tn, 1u);
            if (p < 256u) tlist[p] = ok ? cidx[i] : i;
        }
    }
    __syncthreads();
    if (t == 0) {
        unsigned n2 = (tn < 256u) ? tn : 256u;
        for (unsigned a = 1; a < n2; a++) {
            unsigned key = tlist[a]; int b = (int)a - 1;
            while (b >= 0 && tlist[b] > key) { tlist[b+1] = tlist[b]; b--; }
            tlist[b+1] = key;
        }
        unsigned r = R;
        if (r > n2) r = n2;
        if (r < 1u) r = 1u;
        scut = (n2 > 0u) ? tlist[r - 1] : 0u;
    }
    __syncthreads();
    unsigned cut = scut;
    // ---- write the selected set (order-free; downstream sums order-free) ----
    for (unsigned i = t; i < M; i += 256) {
        unsigned u  = ok ? cval[i] : __float_as_uint(mrow[i]);
        unsigned id = ok ? cidx[i] : i;
        if (u > T || (u == T && id <= cut)) {
            unsigned p = atomicAdd(&ns, 1u);
            if (p < K_SEL) {
                const float* gm = means + ((size_t)row * HW_N + id) * 3;
                float sx = gm[0], sy = gm[1], sz = gm[2];
                float sa = fmaf(sx, sx, fmaf(sy, sy, sz * sz));
                float w  = (u > HALF_BITS) ? sa : -1.0f;
                sampbuf[(size_t)row * K_SEL + p] = make_float4(sx, sy, sz, w);
            }
        }
    }
}

// ---------------------------------------------------------------------------
// Kernel 3: NN partial mins + per-row ticketed reduce + done-ticket finalize.
// 512 blocks = (row, slice of 196); 128 threads; 8 samples/lane in regs ->
// same total ds_read count as R7's proven dist. Last of 8 blocks per row
// reduces the row (fixed-point int64, order-invariant -> deterministic),
// joins the 64-wide done ticket; 64th writes out.
// ---------------------------------------------------------------------------
__global__ void __launch_bounds__(128) dist_red_kernel(
    const float4* __restrict__ meshP, const float4* __restrict__ sampbuf,
    float* __restrict__ minpart, unsigned* __restrict__ rowtick,
    unsigned* __restrict__ ctr, float* __restrict__ out)
{
    __shared__ float4 mq[SLICE];
    __shared__ long long rs[128];
    __shared__ unsigned rc[128];
    __shared__ unsigned stick;
    int blk = blockIdx.x;
    int row = blk >> 3, sl = blk & 7;
    int t = threadIdx.x;

    for (int i = t; i < SLICE; i += 128) mq[i] = meshP[row * NMESH_PAD + sl * SLICE + i];

    const float4* sb = sampbuf + (size_t)row * K_SEL;
    float sx[8], sy[8], sz[8], mn[8];
#pragma unroll
    for (int k = 0; k < 8; k++) {
        float4 s = sb[t + 128*k];
        sx[k] = s.x; sy[k] = s.y; sz[k] = s.z;
        mn[k] = 3.4e38f;
    }
    __syncthreads();

#pragma unroll 2
    for (int i = 0; i < SLICE; i++) {
        float4 a = mq[i];
#pragma unroll
        for (int k = 0; k < 8; k++)
            mn[k] = fminf(mn[k], fmaf(sx[k], a.x, fmaf(sy[k], a.y, fmaf(sz[k], a.z, a.w))));
    }

    float* mp = minpart + ((size_t)row * NSLICE + sl) * K_SEL;
#pragma unroll
    for (int k = 0; k < 8; k++) mp[t + 128*k] = mn[k];

    // ---- per-row ticket: last of the row's 8 blocks reduces the row ----
    __threadfence();                               // release minpart writes
    if (t == 0) stick = atomicAdd(&rowtick[row], 1u);
    __syncthreads();
    if (stick != (unsigned)(NSLICE - 1)) return;
    __threadfence();                               // acquire other blocks' writes

    long long acc = 0; unsigned c = 0;
#pragma unroll
    for (int k = 0; k < 8; k++) {
        int j = k * 128 + t;
        const float* q = minpart + (size_t)row * NSLICE * K_SEL + j;
        float m = q[0];
#pragma unroll
        for (int s = 1; s < NSLICE; s++) m = fminf(m, q[s * (int)K_SEL]);
        float4 sp = sb[j];
        if (sp.w >= 0.0f) {
            float d2 = fmaxf(m + sp.w, 0.0f);
            acc += (long long)((double)d2 * FIX_SCALE);
            c += 1u;
        }
    }
    rs[t] = acc; rc[t] = c;
    __syncthreads();
    for (int off = 64; off > 0; off >>= 1) {
        if (t < off) { rs[t] += rs[t+off]; rc[t] += rc[t+off]; }
        __syncthreads();
    }
    if (t == 0) {
        atomicAdd((u64*)ctr, (u64)rs[0]);
        atomicAdd(&ctr[2], rc[0]);
        __threadfence();
        unsigned dk = atomicAdd(&ctr[3], 1u);
        if (dk == (unsigned)(NROW - 1)) {
            u64 sbits = atomicAdd((u64*)ctr, 0ull);
            unsigned cc = atomicAdd(&ctr[2], 0u);
            double sum = (double)(long long)sbits / FIX_SCALE;
            out[0] = (float)(sum / (double)(cc ? cc : 1u));
        }
    }
}

extern "C" void kernel_launch(void* const* d_in, const int* in_sizes, int n_in,
                              void* d_out, int out_size, void* d_ws, size_t ws_size,
                              hipStream_t stream) {
    const float* hp    = (const float*)d_in[0];
    const float* means = (const float*)d_in[1];
    const float* mask  = (const float*)d_in[2];
    const int*   hv    = (const int*)  d_in[3];
    const float* vtl   = (const float*)d_in[4];
    const float* vtr   = (const float*)d_in[5];
    const float* sdl   = (const float*)d_in[6];
    const float* sdr   = (const float*)d_in[7];
    const float* pdl   = (const float*)d_in[8];
    const float* pdr   = (const float*)d_in[9];
    float* out = (float*)d_out;

    char* ws = (char*)d_ws;
    u64*      cand    = (u64*)(ws + OFF_CAND);
    unsigned* ccnt    = (unsigned*)(ws + OFF_CCNT);
    unsigned* ctr     = (unsigned*)(ws + OFF_CTR);
    unsigned* rowtick = (unsigned*)(ws + OFF_TICK);
    float4*   meshP   = (float4*)(ws + OFF_MESH);
    float4*   sampbuf = (float4*)(ws + OFF_SAMP);
    float*    minpart = (float*)(ws + OFF_MINP);

    combo_kernel<<<1024 + 128, 256, 0, stream>>>(mask, hv, cand, ccnt,
                                                 hp, vtl, vtr, sdl, sdr, pdl, pdr, meshP);
    sel_fin_kernel<<<NROW, 256, 0, stream>>>(mask, means, hv, cand, ccnt,
                                             sampbuf, ctr, rowtick);
    dist_red_kernel<<<NROW * NSLICE, 128, 0, stream>>>(meshP, sampbuf, minpart,
                                                       rowtick, ctr, out);
}

// Round 11
// 49.745 us; speedup vs baseline: 10.8038x; 1.8817x over previous
//
#include <hip/hip_runtime.h>
#include <math.h>

#define HAND_PARAM_DIM 32
#define INF_DIST 1000000.0f
#define EPS 1e-8f
#define NROW 64        // B*S
#define HW_N 65536
#define NV 778
#define NMESH 1556
#define NMESH_PAD 1568  // 16 slices * 98
#define SLICE 98
#define NSLICE 16
#define K_SEL 1024u
#define HALF_BITS  0x3F000000u  // bits of 0.5f
#define GUESS_BITS 0x3F733333u  // bits of 0.95f (speculative collect threshold)
#define TOP_BITS   0x3F800000u  // bits of 1.0f
#define CHUNK_SLOT 512          // per-(row,chunk) candidate capacity (+21 sigma)
#define CAND_MAX   8192         // 16 * CHUNK_SLOT
#define FIX_SCALE 4294967296.0  // 2^32 fixed-point scale

// ---- workspace layout (bytes) ----
#define OFF_CAND 0u             // 64*16*512*8 = 4194304
#define OFF_CCNT 4194304u       // 64*16*4     = 4096
#define OFF_CTR  4198400u       // 4 u32: gsum(2), gcnt, done (8-aligned)
#define OFF_MESH 4198416u       // 64*1568*16  = 1605632 (16-aligned)
#define OFF_SAMP 5804048u       // 64*1024*16  = 1048576
#define OFF_MINP 6852624u       // 64*16*1024*4 = 4194304

typedef unsigned long long u64;

// ---------------------------------------------------------------------------
// Kernel 1: blocks 0..1023 = speculative collect (one mask pass, NO global
// atomics); blocks 1024..1151 = MANO mesh points. (byte-for-byte the 57us
// version). Mesh pre-scaled: m.xyz = -2*p, m.w = |p|^2.
// ---------------------------------------------------------------------------
__global__ void __launch_bounds__(256) combo_kernel(
    const float* __restrict__ mask, const int* __restrict__ hv,
    u64* __restrict__ cand, unsigned* __restrict__ ccnt,
    const float* __restrict__ hp,
    const float* __restrict__ vtl, const float* __restrict__ vtr,
    const float* __restrict__ sdl, const float* __restrict__ sdr,
    const float* __restrict__ pdl, const float* __restrict__ pdr,
    float4* __restrict__ meshP)
{
    int blk = blockIdx.x;
    int t = threadIdx.x;

    if (blk < 1024) {
        __shared__ u64 loc[CHUNK_SLOT];
        __shared__ unsigned nc, nbad;
        int row = blk >> 4, chunk = blk & 15;
        if (!(hv[row*2] | hv[row*2+1])) return;
        if (t == 0) { nc = 0u; nbad = 0u; }
        __syncthreads();
        const float4* m4 = (const float4*)(mask + (size_t)row * HW_N + chunk * 4096);
#pragma unroll
        for (int k = 0; k < 4; k++) {
            float4 v = m4[k*256 + t];
            unsigned e0 = (unsigned)(chunk*4096 + (k*256 + t)*4);
            unsigned u;
#define PROC(comp, off_) { u = __float_as_uint(comp); \
            if (u >= GUESS_BITS) { \
                unsigned p_ = atomicAdd(&nc, 1u); \
                if (p_ < CHUNK_SLOT) loc[p_] = ((u64)u << 32) | (e0 + off_); \
                if (u >= TOP_BITS) nbad = 1u; } }
            PROC(v.x, 0u) PROC(v.y, 1u) PROC(v.z, 2u) PROC(v.w, 3u)
#undef PROC
        }
        __syncthreads();
        unsigned n = (nc < CHUNK_SLOT) ? nc : CHUNK_SLOT;
        if (t == 0) ccnt[row*16 + chunk] = nc | (nbad << 31);
        u64* dst = cand + ((size_t)(row*16 + chunk)) * CHUNK_SLOT;
        for (unsigned i = t; i < n; i += 256) dst[i] = loc[i];
        return;
    }

    // ---- mesh points ----
    int mb   = blk - 1024;
    int row  = mb >> 1;
    int hand = mb & 1;
    const float* p = hp + row * (2 * HAND_PARAM_DIM) + hand * HAND_PARAM_DIM;
    int valid = hv[row * 2 + hand];

    const float* vt = hand ? vtr : vtl;
    const float* sd = hand ? sdr : sdl;
    const float* pd = hand ? pdr : pdl;

    if (hand == 1 && t < (NMESH_PAD - NMESH))
        meshP[row * NMESH_PAD + NMESH + t] = make_float4(0.f, 0.f, 0.f, 3.4e38f);

    float tx = p[0], ty = p[1], tz = p[2];
    float q0 = p[3], q1 = p[4], q2 = p[5], q3 = p[6];
    float qn = sqrtf(q0*q0 + q1*q1 + q2*q2 + q3*q3 + EPS);
    float inv = 1.0f / fmaxf(qn, EPS);
    q0 *= inv; q1 *= inv; q2 *= inv; q3 *= inv;
    float sgn = (q0 < 0.0f) ? -1.0f : 1.0f;
    q0 *= sgn; q1 *= sgn; q2 *= sgn; q3 *= sgn;
    float sin_half = sqrtf(q1*q1 + q2*q2 + q3*q3 + EPS);
    float w_safe = fminf(fmaxf(q0, -1.0f + EPS), 1.0f - EPS);
    float ang2 = 2.0f * atan2f(sin_half, w_safe);
    float factor = (sin_half < 1e-6f) ? 2.0f : ang2 / fmaxf(sin_half, EPS);
    float rx = q1 * factor, ry = q2 * factor, rz = q3 * factor;
    float ang = sqrtf(rx*rx + ry*ry + rz*rz + EPS);
    float iang = 1.0f / ang;
    float ax = rx * iang, ay = ry * iang, az = rz * iang;
    float c = cosf(ang), s = sinf(ang), omc = 1.0f - c;

    float pose[15], betas[10];
#pragma unroll
    for (int k = 0; k < 15; k++) pose[k] = p[7 + k];
#pragma unroll
    for (int k = 0; k < 10; k++) betas[k] = p[22 + k];

    for (int v = t; v < NV; v += 256) {
        float px = vt[v*3+0], py = vt[v*3+1], pz = vt[v*3+2];
        const float* sdv = sd + v * 30;
#pragma unroll
        for (int k = 0; k < 10; k++) {
            px = fmaf(sdv[k],      betas[k], px);
            py = fmaf(sdv[10 + k], betas[k], py);
            pz = fmaf(sdv[20 + k], betas[k], pz);
        }
        const float* pdv = pd + v * 45;
#pragma unroll
        for (int k = 0; k < 15; k++) {
            px = fmaf(pdv[k],      pose[k], px);
            py = fmaf(pdv[15 + k], pose[k], py);
            pz = fmaf(pdv[30 + k], pose[k], pz);
        }
        float cx = ay * pz - az * py;
        float cy = az * px - ax * pz;
        float cz = ax * py - ay * px;
        float kdv = ax * px + ay * py + az * pz;
        float ox = px * c + cx * s + ax * kdv * omc + tx;
        float oy = py * c + cy * s + ay * kdv * omc + ty;
        float oz = pz * c + cz * s + az * kdv * omc + tz;
        if (!valid) { ox = INF_DIST; oy = INF_DIST; oz = INF_DIST; }
        float sb = fmaf(ox, ox, fmaf(oy, oy, oz * oz));
        meshP[row * NMESH_PAD + hand * NV + v] = make_float4(-2.0f*ox, -2.0f*oy, -2.0f*oz, sb);
    }
}

// ---------------------------------------------------------------------------
// Kernel 2: per-row exact top-1024 (byte-for-byte the 57us version).
// Fast path: 2-phase radix on (bits - GUESS_BITS); generic 4-phase fallback.
// Emits sampbuf[row][i] = (x,y,z, val>0.5?|s|^2:-1). Block 0 zeroes ctr.
// ---------------------------------------------------------------------------
__global__ void __launch_bounds__(256) sel_fin_kernel(
    const float* __restrict__ mask, const float* __restrict__ means,
    const int* __restrict__ hv,
    const u64* __restrict__ cand, const unsigned* __restrict__ ccnt,
    float4* __restrict__ sampbuf, unsigned* __restrict__ ctr)
{
    __shared__ unsigned cval[CAND_MAX], cidx[CAND_MAX];   // 64 KB
    __shared__ unsigned h[256], seg[256];
    __shared__ unsigned csub[16], cbase[16];
    __shared__ unsigned sbin, sRn, sbad, stot;
    __shared__ unsigned tlist[256];
    __shared__ unsigned tn, ns, scut;
    int row = blockIdx.x, t = threadIdx.x;

    if (row == 0 && t < 4) ctr[t] = 0u;          // gsum lo/hi, gcnt, done
    for (unsigned i = t; i < K_SEL; i += 256)
        sampbuf[(size_t)row * K_SEL + i] = make_float4(0.f, 0.f, 0.f, -1.0f);
    if (!(hv[row*2] | hv[row*2+1])) return;

    if (t == 0) { sbad = 0u; tn = 0u; ns = 0u; }
    __syncthreads();
    if (t < 16) {
        unsigned w = ccnt[row*16 + t];
        unsigned n = w & 0x7FFFFFFFu;
        csub[t] = (n < CHUNK_SLOT) ? n : CHUNK_SLOT;
        if ((w >> 31) || n > CHUNK_SLOT) atomicOr(&sbad, 1u);
    }
    __syncthreads();
    if (t == 0) {
        unsigned run = 0;
#pragma unroll
        for (int c = 0; c < 16; c++) { cbase[c] = run; run += csub[c]; }
        stot = run;
    }
    __syncthreads();
    unsigned cnt = stot;
    bool ok = (sbad == 0u) && (cnt >= K_SEL) && (cnt <= CAND_MAX);
    const float* mrow = mask + (size_t)row * HW_N;
    unsigned M = ok ? cnt : (unsigned)HW_N;

    if (ok) {
#pragma unroll
        for (int c = 0; c < 16; c++) {
            unsigned n = csub[c], b = cbase[c];
            const u64* src = cand + ((size_t)(row*16 + c)) * CHUNK_SLOT;
            for (unsigned i = t; i < n; i += 256) {
                u64 e = src[i];
                cval[b + i] = (unsigned)(e >> 32); cidx[b + i] = (unsigned)e;
            }
        }
    }
    __syncthreads();

    unsigned T, R;
    if (ok) {
        unsigned pfx = 0u; R = K_SEL;
        for (int ph = 0; ph < 2; ph++) {
            int sh = 8 * (1 - ph);
            h[t] = 0u;
            __syncthreads();
            for (unsigned i = t; i < cnt; i += 256) {
                unsigned off = cval[i] - GUESS_BITS;
                if (ph == 0 || (off >> 8) == pfx) atomicAdd(&h[(off >> sh) & 0xFFu], 1u);
            }
            __syncthreads();
            seg[t] = h[t];
            __syncthreads();
            for (int off2 = 1; off2 < 256; off2 <<= 1) {   // inclusive suffix scan
                unsigned v = (t + off2 < 256) ? seg[t + off2] : 0u;
                __syncthreads(); seg[t] += v; __syncthreads();
            }
            unsigned excl = (t < 255) ? seg[t + 1] : 0u;
            if (excl < R && R <= seg[t]) { sbin = (unsigned)t; sRn = R - excl; }
            __syncthreads();
            pfx = (ph == 0) ? sbin : ((pfx << 8) | sbin);
            R = sRn;
            __syncthreads();
        }
        T = GUESS_BITS + pfx;
    } else {
        unsigned pfx = 0u; R = K_SEL;
        for (int ph = 0; ph < 4; ph++) {
            int sh = 24 - 8 * ph;
            unsigned pm = (ph == 0) ? 0u : (0xFFFFFFFFu << (sh + 8));
            h[t] = 0u;
            __syncthreads();
            for (unsigned i = t; i < M; i += 256) {
                unsigned u = __float_as_uint(mrow[i]);
                if ((u & pm) == pfx) atomicAdd(&h[(u >> sh) & 0xFFu], 1u);
            }
            __syncthreads();
            seg[t] = h[t];
            __syncthreads();
            for (int off2 = 1; off2 < 256; off2 <<= 1) {
                unsigned v = (t + off2 < 256) ? seg[t + off2] : 0u;
                __syncthreads(); seg[t] += v; __syncthreads();
            }
            unsigned excl = (t < 255) ? seg[t + 1] : 0u;
            if (excl < R && R <= seg[t]) { sbin = (unsigned)t; sRn = R - excl; }
            __syncthreads();
            pfx |= sbin << sh;
            R = sRn;
            __syncthreads();
        }
        T = pfx;
    }

    // ---- ties at exact value T -> R-th smallest index is the cut ----
    for (unsigned i = t; i < M; i += 256) {
        unsigned u = ok ? cval[i] : __float_as_uint(mrow[i]);
        if (u == T) {
            unsigned p = atomicAdd(&tn, 1u);
            if (p < 256u) tlist[p] = ok ? cidx[i] : i;
        }
    }
    __syncthreads();
    if (t == 0) {
        unsigned n2 = (tn < 256u) ? tn : 256u;
        for (unsigned a = 1; a < n2; a++) {
            unsigned key = tlist[a]; int b = (int)a - 1;
            while (b >= 0 && tlist[b] > key) { tlist[b+1] = tlist[b]; b--; }
            tlist[b+1] = key;
        }
        unsigned r = R;
        if (r > n2) r = n2;
        if (r < 1u) r = 1u;
        scut = (n2 > 0u) ? tlist[r - 1] : 0u;
    }
    __syncthreads();
    unsigned cut = scut;
    // ---- write the selected set (order-free; downstream sums order-free) ----
    for (unsigned i = t; i < M; i += 256) {
        unsigned u  = ok ? cval[i] : __float_as_uint(mrow[i]);
        unsigned id = ok ? cidx[i] : i;
        if (u > T || (u == T && id <= cut)) {
            unsigned p = atomicAdd(&ns, 1u);
            if (p < K_SEL) {
                const float* gm = means + ((size_t)row * HW_N + id) * 3;
                float sx = gm[0], sy = gm[1], sz = gm[2];
                float sa = fmaf(sx, sx, fmaf(sy, sy, sz * sz));
                float w  = (u > HALF_BITS) ? sa : -1.0f;
                sampbuf[(size_t)row * K_SEL + p] = make_float4(sx, sy, sz, w);
            }
        }
    }
}

// ---------------------------------------------------------------------------
// Kernel 3: NN partial mins. 1024 blocks, XCD-affine: blk = sl*64 + row so
// all 16 slice-blocks of row r land on XCD r%8 (64%8==0) -> minpart/sampbuf
// row stays in one L2. 256 threads, 4 samples/lane (16 waves/CU). No atomics,
// no fences.
// ---------------------------------------------------------------------------
__global__ void __launch_bounds__(256) dist_kernel(
    const float4* __restrict__ meshP, const float4* __restrict__ sampbuf,
    float* __restrict__ minpart)
{
    __shared__ float4 mq[SLICE];
    int blk = blockIdx.x;
    int r = blk & 63, sl = blk >> 6;          // XCD-affine mapping
    int t = threadIdx.x;

    if (t < SLICE) mq[t] = meshP[r * NMESH_PAD + sl * SLICE + t];

    const float4* sb = sampbuf + (size_t)r * K_SEL;
    float sx[4], sy[4], sz[4], mn[4];
#pragma unroll
    for (int k = 0; k < 4; k++) {
        float4 s = sb[t + 256*k];
        sx[k] = s.x; sy[k] = s.y; sz[k] = s.z;
        mn[k] = 3.4e38f;
    }
    __syncthreads();

#pragma unroll 2
    for (int i = 0; i < SLICE; i++) {
        float4 a = mq[i];
#pragma unroll
        for (int k = 0; k < 4; k++)
            mn[k] = fminf(mn[k], fmaf(sx[k], a.x, fmaf(sy[k], a.y, fmaf(sz[k], a.z, a.w))));
    }

    float* mp = minpart + ((size_t)r * NSLICE + sl) * K_SEL;
#pragma unroll
    for (int k = 0; k < 4; k++) mp[t + 256*k] = mn[k];
}

// ---------------------------------------------------------------------------
// Kernel 4: per-sample min over 16 slices + per-row fixed-point sum +
// last-of-64 ticket finalize (64 fences total -- proven cheap). Block r reads
// its row's minpart from the same XCD L2 (r%8). Integer adds -> deterministic.
// ---------------------------------------------------------------------------
__global__ void __launch_bounds__(256) reduce_kernel(
    const float* __restrict__ minpart, const float4* __restrict__ sampbuf,
    unsigned* __restrict__ ctr, float* __restrict__ out)
{
    __shared__ long long rs[256];
    __shared__ unsigned rc[256];
    int row = blockIdx.x;
    int t = threadIdx.x;

    long long acc = 0; unsigned c = 0;
#pragma unroll
    for (int k = 0; k < 4; k++) {
        int j = k * 256 + t;
        const float* mp = minpart + (size_t)row * NSLICE * K_SEL + j;
        float m = mp[0];
#pragma unroll
        for (int s = 1; s < NSLICE; s++) m = fminf(m, mp[s * (int)K_SEL]);
        float4 sp = sampbuf[(size_t)row * K_SEL + j];
        if (sp.w >= 0.0f) {
            float d2 = fmaxf(m + sp.w, 0.0f);
            acc += (long long)((double)d2 * FIX_SCALE);
            c += 1u;
        }
    }
    rs[t] = acc; rc[t] = c;
    __syncthreads();
    for (int off = 128; off > 0; off >>= 1) {
        if (t < off) { rs[t] += rs[t+off]; rc[t] += rc[t+off]; }
        __syncthreads();
    }
    if (t == 0) {
        atomicAdd((u64*)ctr, (u64)rs[0]);
        atomicAdd(&ctr[2], rc[0]);
        __threadfence();
        unsigned tk = atomicAdd(&ctr[3], 1u);
        if (tk == (unsigned)(NROW - 1)) {
            u64 sbits = atomicAdd((u64*)ctr, 0ull);
            unsigned cc = atomicAdd(&ctr[2], 0u);
            double sum = (double)(long long)sbits / FIX_SCALE;
            out[0] = (float)(sum / (double)(cc ? cc : 1u));
        }
    }
}

extern "C" void kernel_launch(void* const* d_in, const int* in_sizes, int n_in,
                              void* d_out, int out_size, void* d_ws, size_t ws_size,
                              hipStream_t stream) {
    const float* hp    = (const float*)d_in[0];
    const float* means = (const float*)d_in[1];
    const float* mask  = (const float*)d_in[2];
    const int*   hv    = (const int*)  d_in[3];
    const float* vtl   = (const float*)d_in[4];
    const float* vtr   = (const float*)d_in[5];
    const float* sdl   = (const float*)d_in[6];
    const float* sdr   = (const float*)d_in[7];
    const float* pdl   = (const float*)d_in[8];
    const float* pdr   = (const float*)d_in[9];
    float* out = (float*)d_out;

    char* ws = (char*)d_ws;
    u64*      cand    = (u64*)(ws + OFF_CAND);
    unsigned* ccnt    = (unsigned*)(ws + OFF_CCNT);
    unsigned* ctr     = (unsigned*)(ws + OFF_CTR);
    float4*   meshP   = (float4*)(ws + OFF_MESH);
    float4*   sampbuf = (float4*)(ws + OFF_SAMP);
    float*    minpart = (float*)(ws + OFF_MINP);

    combo_kernel<<<1024 + 128, 256, 0, stream>>>(mask, hv, cand, ccnt,
                                                 hp, vtl, vtr, sdl, sdr, pdl, pdr, meshP);
    sel_fin_kernel<<<NROW, 256, 0, stream>>>(mask, means, hv, cand, ccnt, sampbuf, ctr);
    dist_kernel<<<NROW * NSLICE, 256, 0, stream>>>(meshP, sampbuf, minpart);
    reduce_kernel<<<NROW, 256, 0, stream>>>(minpart, sampbuf, ctr, out);
}